// Round 6
// baseline (86.796 us; speedup 1.0000x reference)
//
#include <hip/hip_runtime.h>

#define NN 50000
#define NE 800000
#define D  64
#define NB 196            // bins of 256 nodes: bin = dst >> 8
#define EBLK 2048         // edges per K1/K3 block
#define NEB 391           // ceil(NE / EBLK)
#define K4CAP 2048        // LDS edge-staging cap per 64-node block (mean 1024)

typedef unsigned int u32;
typedef unsigned long long u64;

// record: [dst:16][src:16][w_bits:32]
__device__ __forceinline__ int wave_incl_scan(int v, int lane) {
    #pragma unroll
    for (int off = 1; off < 64; off <<= 1) {
        int t = __shfl_up(v, off);
        if (lane >= off) v += t;
    }
    return v;
}

__device__ __forceinline__ u32 f2bf(float x) {       // RNE bf16, returns low 16
    u32 u = __float_as_uint(x);
    return (u + 0x7fffu + ((u >> 16) & 1u)) >> 16;
}

// ---------------------------------------------------------------------------
// conv: feat (fp32) -> featb (bf16), 8 features per thread, uint4 stores.
// Layout: feature pair (2j, 2j+1) packed lo|hi in u32 j of the row.
// ---------------------------------------------------------------------------
__global__ __launch_bounds__(256) void conv_kernel(const float* __restrict__ feat,
                                                   uint4* __restrict__ featb)
{
    int i = blockIdx.x * 256 + threadIdx.x;          // < NN*D/8 = 400000
    if (i >= NN * D / 8) return;
    const float4* f4 = (const float4*)feat;
    float4 a = f4[2 * i], b = f4[2 * i + 1];
    uint4 o;
    o.x = f2bf(a.x) | (f2bf(a.y) << 16);
    o.y = f2bf(a.z) | (f2bf(a.w) << 16);
    o.z = f2bf(b.x) | (f2bf(b.y) << 16);
    o.w = f2bf(b.z) | (f2bf(b.w) << 16);
    featb[i] = o;
}

// ---------------------------------------------------------------------------
// K1: per-block histogram over 196 bins (LDS atomics, coalesced global write)
// ---------------------------------------------------------------------------
__global__ __launch_bounds__(256) void k1_hist(const int* __restrict__ dst,
                                               u32* __restrict__ ghist)
{
    __shared__ u32 h[NB];
    int tid = threadIdx.x;
    if (tid < NB) h[tid] = 0;
    __syncthreads();
    int base = blockIdx.x * EBLK;
    int n = min(EBLK, NE - base);
    for (int k = tid; k < n; k += 256)
        atomicAdd(&h[((u32)dst[base + k]) >> 8], 1u);
    __syncthreads();
    if (tid < NB) ghist[blockIdx.x * NB + tid] = h[tid];
}

// ---------------------------------------------------------------------------
// K2: per-bin exclusive scan over the 391 block counts -> bbase[blk][bin],
// plus bin totals. One wave per bin.
// ---------------------------------------------------------------------------
__global__ __launch_bounds__(256) void k2_scan(const u32* __restrict__ ghist,
                                               u32* __restrict__ bbase,
                                               u32* __restrict__ binTot)
{
    int gw = (blockIdx.x * 256 + threadIdx.x) >> 6;
    int lane = threadIdx.x & 63;
    if (gw >= NB) return;
    u32 run = 0;
    for (int c = 0; c < 7; ++c) {              // 7*64 = 448 >= 391
        int blk = c * 64 + lane;
        u32 v = (blk < NEB) ? ghist[blk * NB + gw] : 0;
        int incl = wave_incl_scan((int)v, lane);
        if (blk < NEB) bbase[blk * NB + gw] = (u32)incl - v + run;
        run += (u32)__shfl(incl, 63);
    }
    if (lane == 0) binTot[gw] = run;
}

// K2b: exclusive scan of 196 bin totals -> binStart[0..196]
__global__ void k2b_scan(const u32* __restrict__ binTot, u32* __restrict__ binStart)
{
    int lane = threadIdx.x;
    if (lane < 64) {
        u32 carry = 0;
        for (int c = 0; c < 4; ++c) {
            int idx = c * 64 + lane;
            u32 v = (idx < NB) ? binTot[idx] : 0;
            int incl = wave_incl_scan((int)v, lane);
            if (idx <= NB) binStart[idx] = (u32)incl - v + carry;
            carry += (u32)__shfl(incl, 63);
        }
    }
}

// ---------------------------------------------------------------------------
// K3: stable-ish bin scatter with LDS reorder -> mostly-coalesced writes.
// ---------------------------------------------------------------------------
__global__ __launch_bounds__(256) void k3_scatter(const int* __restrict__ src,
                                                  const int* __restrict__ dst,
                                                  const float* __restrict__ ew,
                                                  const u32* __restrict__ bbase,
                                                  const u32* __restrict__ binStart,
                                                  u64* __restrict__ sorted)
{
    __shared__ u32 h[NB], eb[NB], ctr[NB], gb[NB];
    __shared__ u64 buf[EBLK];
    int tid = threadIdx.x;
    if (tid < NB) h[tid] = 0;
    __syncthreads();
    int base = blockIdx.x * EBLK;
    int n = min(EBLK, NE - base);
    for (int k = tid; k < n; k += 256)
        atomicAdd(&h[((u32)dst[base + k]) >> 8], 1u);
    __syncthreads();
    if (tid < 64) {
        u32 carry = 0;
        for (int c = 0; c < 4; ++c) {          // 4*64 = 256 >= 196
            int idx = c * 64 + tid;
            u32 v = (idx < NB) ? h[idx] : 0;
            int incl = wave_incl_scan((int)v, tid);
            if (idx < NB) { u32 e = (u32)incl - v + carry; eb[idx] = e; ctr[idx] = e; }
            carry += (u32)__shfl(incl, 63);
        }
    }
    if (tid < NB) gb[tid] = bbase[blockIdx.x * NB + tid] + binStart[tid];
    __syncthreads();
    for (int k = tid; k < n; k += 256) {
        int e = base + k;
        u32 d = (u32)dst[e], s = (u32)src[e];
        u64 rec = ((u64)((d << 16) | s) << 32) | (u64)__float_as_uint(ew[e]);
        u32 p = atomicAdd(&ctr[d >> 8], 1u);
        buf[p] = rec;
    }
    __syncthreads();
    for (int k = tid; k < n; k += 256) {
        u64 rec = buf[k];
        u32 bin = (u32)(rec >> 56);            // dst>>8
        sorted[gb[bin] + (u32)k - eb[bin]] = rec;
    }
}

// ---------------------------------------------------------------------------
// K4: fused per-node CSR build (in LDS) + register gather of bf16 feat rows.
// Block owns 64 nodes (quarter of a bin); scans bin's contiguous records.
// Each wave: 16 nodes serial; per node 4x16-lane groups, 4-deep unroll
// -> 16 independent 128B row loads in flight per wave.
// ---------------------------------------------------------------------------
__global__ __launch_bounds__(256) void k4_gather(const uint2* __restrict__ fb,
                                                 const u64* __restrict__ sorted,
                                                 const u32* __restrict__ binStart,
                                                 float* __restrict__ agg,
                                                 float* __restrict__ sW)
{
    __shared__ u32 cnt[64], cbase[65], ctr[64];
    __shared__ u32 bs[K4CAP];
    __shared__ float bw[K4CAP];
    int tid = threadIdx.x;
    int nodeBase = blockIdx.x * 64;
    int bin = blockIdx.x >> 2;
    int beg = (int)binStart[bin], end = (int)binStart[bin + 1];

    if (tid < 64) cnt[tid] = 0;
    __syncthreads();
    for (int i = beg + tid; i < end; i += 256) {
        u64 rec = sorted[i];
        int ln = (int)(rec >> 48) - nodeBase;
        if (ln >= 0 && ln < 64) atomicAdd(&cnt[ln], 1u);
    }
    __syncthreads();
    if (tid < 64) {
        int incl = wave_incl_scan((int)cnt[tid], tid);
        u32 e = (u32)incl - cnt[tid];
        cbase[tid] = e; ctr[tid] = e;
        if (tid == 63) cbase[64] = (u32)incl;
    }
    __syncthreads();
    for (int i = beg + tid; i < end; i += 256) {
        u64 rec = sorted[i];
        int ln = (int)(rec >> 48) - nodeBase;
        if (ln >= 0 && ln < 64) {
            u32 p = atomicAdd(&ctr[ln], 1u);
            if (p < K4CAP) {
                bs[p] = (u32)(rec >> 32) & 0xffffu;
                bw[p] = __uint_as_float((u32)rec);
            }
        }
    }
    __syncthreads();

    int lane = tid & 63, w = tid >> 6;
    int g = lane >> 4, li = lane & 15;
    for (int t = 0; t < 16; ++t) {
        int ln = w * 16 + t;
        int node = nodeBase + ln;
        int b0 = min((int)cbase[ln], K4CAP);
        int b1 = min((int)cbase[ln + 1], K4CAP);
        float4 acc = make_float4(0.f, 0.f, 0.f, 0.f);
        float ws = 0.f;
        int e = b0 + g;
        for (; e + 12 < b1; e += 16) {
            int s0 = bs[e], s1 = bs[e + 4], s2 = bs[e + 8], s3 = bs[e + 12];
            ws += bw[e] + bw[e + 4] + bw[e + 8] + bw[e + 12];
            uint2 u0 = fb[(size_t)s0 * 16 + li];
            uint2 u1 = fb[(size_t)s1 * 16 + li];
            uint2 u2 = fb[(size_t)s2 * 16 + li];
            uint2 u3 = fb[(size_t)s3 * 16 + li];
            acc.x += __uint_as_float(u0.x << 16) + __uint_as_float(u1.x << 16)
                   + __uint_as_float(u2.x << 16) + __uint_as_float(u3.x << 16);
            acc.y += __uint_as_float(u0.x & 0xffff0000u) + __uint_as_float(u1.x & 0xffff0000u)
                   + __uint_as_float(u2.x & 0xffff0000u) + __uint_as_float(u3.x & 0xffff0000u);
            acc.z += __uint_as_float(u0.y << 16) + __uint_as_float(u1.y << 16)
                   + __uint_as_float(u2.y << 16) + __uint_as_float(u3.y << 16);
            acc.w += __uint_as_float(u0.y & 0xffff0000u) + __uint_as_float(u1.y & 0xffff0000u)
                   + __uint_as_float(u2.y & 0xffff0000u) + __uint_as_float(u3.y & 0xffff0000u);
        }
        for (; e < b1; e += 4) {
            int s0 = bs[e];
            ws += bw[e];
            uint2 u0 = fb[(size_t)s0 * 16 + li];
            acc.x += __uint_as_float(u0.x << 16);
            acc.y += __uint_as_float(u0.x & 0xffff0000u);
            acc.z += __uint_as_float(u0.y << 16);
            acc.w += __uint_as_float(u0.y & 0xffff0000u);
        }
        acc.x += __shfl_xor(acc.x, 16); acc.x += __shfl_xor(acc.x, 32);
        acc.y += __shfl_xor(acc.y, 16); acc.y += __shfl_xor(acc.y, 32);
        acc.z += __shfl_xor(acc.z, 16); acc.z += __shfl_xor(acc.z, 32);
        acc.w += __shfl_xor(acc.w, 16); acc.w += __shfl_xor(acc.w, 32);
        ws += __shfl_xor(ws, 16); ws += __shfl_xor(ws, 32);
        if (g == 0 && node < NN) {
            *(float4*)&agg[(size_t)node * D + li * 4] = acc;
            if (li == 0) sW[node] = ws;
        }
    }
}

// ---------------------------------------------------------------------------
// Epilogue GEMM: out = feat@W1 + agg@W2 - sW ⊗ colsum(W2)
// ---------------------------------------------------------------------------
__global__ __launch_bounds__(256) void gemm_kernel(
    const float* __restrict__ feat,
    const float* __restrict__ agg,
    const float* __restrict__ sW,
    const float* __restrict__ W1,
    const float* __restrict__ W2,
    float* __restrict__ out)
{
    __shared__ float As[64][68];
    __shared__ float Bs[64][68];
    __shared__ float w1s[64 * 64];
    __shared__ float w2s[64 * 64];
    __shared__ float csum[64];
    __shared__ float swS[64];

    const int t = threadIdx.x;
    const int r0 = blockIdx.x * 64;
    const float4 z4 = make_float4(0.f, 0.f, 0.f, 0.f);

    for (int idx = t; idx < 1024; idx += 256) {
        int r = idx >> 4, c4 = idx & 15;
        int gr = r0 + r;
        float4 fv = z4, av = z4;
        if (gr < NN) {
            fv = *(const float4*)&feat[(size_t)gr * D + c4 * 4];
            av = *(const float4*)&agg [(size_t)gr * D + c4 * 4];
        }
        *(float4*)&As[r][c4 * 4] = fv;
        *(float4*)&Bs[r][c4 * 4] = av;
        ((float4*)w1s)[idx] = ((const float4*)W1)[idx];
        ((float4*)w2s)[idx] = ((const float4*)W2)[idx];
    }
    if (t < 64) swS[t] = (r0 + t < NN) ? sW[r0 + t] : 0.f;
    __syncthreads();
    if (t < 64) {
        float c = 0.f;
        for (int k = 0; k < 64; ++k) c += w2s[k * 64 + t];
        csum[t] = c;
    }
    __syncthreads();

    const int cg = t & 15;
    const int rg = t >> 4;
    const int j0 = cg * 4;
    const float4* w1v = (const float4*)w1s;
    const float4* w2v = (const float4*)w2s;

    float acc[4][4] = {};

    #pragma unroll 4
    for (int k4 = 0; k4 < 16; ++k4) {
        float4 av[4];
        #pragma unroll
        for (int i = 0; i < 4; ++i) av[i] = *(const float4*)&As[rg * 4 + i][k4 * 4];
        #pragma unroll
        for (int kk = 0; kk < 4; ++kk) {
            float4 wv = w1v[(k4 * 4 + kk) * 16 + cg];
            #pragma unroll
            for (int i = 0; i < 4; ++i) {
                float a = (&av[i].x)[kk];
                acc[i][0] += a * wv.x; acc[i][1] += a * wv.y;
                acc[i][2] += a * wv.z; acc[i][3] += a * wv.w;
            }
        }
    }
    #pragma unroll 4
    for (int k4 = 0; k4 < 16; ++k4) {
        float4 av[4];
        #pragma unroll
        for (int i = 0; i < 4; ++i) av[i] = *(const float4*)&Bs[rg * 4 + i][k4 * 4];
        #pragma unroll
        for (int kk = 0; kk < 4; ++kk) {
            float4 wv = w2v[(k4 * 4 + kk) * 16 + cg];
            #pragma unroll
            for (int i = 0; i < 4; ++i) {
                float a = (&av[i].x)[kk];
                acc[i][0] += a * wv.x; acc[i][1] += a * wv.y;
                acc[i][2] += a * wv.z; acc[i][3] += a * wv.w;
            }
        }
    }

    #pragma unroll
    for (int i = 0; i < 4; ++i) {
        int r = rg * 4 + i, gr = r0 + r;
        if (gr < NN) {
            float s = swS[r];
            float4 o;
            o.x = acc[i][0] - s * csum[j0 + 0];
            o.y = acc[i][1] - s * csum[j0 + 1];
            o.z = acc[i][2] - s * csum[j0 + 2];
            o.w = acc[i][3] - s * csum[j0 + 3];
            *(float4*)&out[(size_t)gr * D + j0] = o;
        }
    }
}

// ---------------------------------------------------------------------------
extern "C" void kernel_launch(void* const* d_in, const int* in_sizes, int n_in,
                              void* d_out, int out_size, void* d_ws, size_t ws_size,
                              hipStream_t stream)
{
    const float* feat = (const float*)d_in[0];
    const float* ew   = (const float*)d_in[1];
    const float* W1   = (const float*)d_in[2];
    const float* W2   = (const float*)d_in[3];
    const int*   src  = (const int*)  d_in[4];
    const int*   dst  = (const int*)  d_in[5];
    float* out = (float*)d_out;

    // workspace layout (~27 MB of the 256 MB d_ws; all fully written before read)
    char* p = (char*)d_ws;
    size_t o = 0;
    auto take = [&](size_t bytes) { char* q = p + o; o = (o + bytes + 255) & ~(size_t)255; return q; };
    u64* sorted   = (u64*)take((size_t)NE * 8);             // 6.4 MB
    u32* ghist    = (u32*)take((size_t)NEB * NB * 4);       // 306 KB
    u32* bbase    = (u32*)take((size_t)NEB * NB * 4);       // 306 KB
    u32* binTot   = (u32*)take((size_t)NB * 4);
    u32* binStart = (u32*)take((size_t)(NB + 1) * 4);
    float* agg    = (float*)take((size_t)NN * D * 4);       // 12.8 MB
    float* sW     = (float*)take((size_t)NN * 4);           // 200 KB
    uint4* featb  = (uint4*)take((size_t)NN * D * 2);       // 6.4 MB bf16 copy

    conv_kernel<<<(NN * D / 8 + 255) / 256, 256, 0, stream>>>(feat, featb);
    k1_hist    <<<NEB, 256, 0, stream>>>(dst, ghist);
    k2_scan    <<<(NB * 64 + 255) / 256, 256, 0, stream>>>(ghist, bbase, binTot);
    k2b_scan   <<<1, 256, 0, stream>>>(binTot, binStart);
    k3_scatter <<<NEB, 256, 0, stream>>>(src, dst, ew, bbase, binStart, sorted);
    k4_gather  <<<(NN + 63) / 64, 256, 0, stream>>>((const uint2*)featb, sorted,
                                                    binStart, agg, sW);
    gemm_kernel<<<(NN + 63) / 64, 256, 0, stream>>>(feat, agg, sW, W1, W2, out);
}

// Round 7
// 81.529 us; speedup vs baseline: 1.0646x; 1.0646x over previous
//
#include <hip/hip_runtime.h>

#define NN 50000
#define NE 800000
#define D  64
#define NB 196            // bins of 256 nodes: bin = dst >> 8
#define EBLK 2048         // edges per K1/K3 block
#define NEB 391           // ceil(NE / EBLK)
#define CAP3B 4608        // per-bin record cap for k3b LDS (mean 4082, 8-sigma)

typedef unsigned int u32;
typedef unsigned long long u64;

// record: [dst:16][src:16][w_bits:32]
__device__ __forceinline__ int wave_incl_scan(int v, int lane) {
    #pragma unroll
    for (int off = 1; off < 64; off <<= 1) {
        int t = __shfl_up(v, off);
        if (lane >= off) v += t;
    }
    return v;
}

__device__ __forceinline__ u32 f2bf(float x) {       // RNE bf16, returns low 16
    u32 u = __float_as_uint(x);
    return (u + 0x7fffu + ((u >> 16) & 1u)) >> 16;
}

// ---------------------------------------------------------------------------
// conv: feat (fp32) -> featb (bf16), 8 features per thread, uint4 stores.
// ---------------------------------------------------------------------------
__global__ __launch_bounds__(256) void conv_kernel(const float* __restrict__ feat,
                                                   uint4* __restrict__ featb)
{
    int i = blockIdx.x * 256 + threadIdx.x;          // < NN*D/8 = 400000
    if (i >= NN * D / 8) return;
    const float4* f4 = (const float4*)feat;
    float4 a = f4[2 * i], b = f4[2 * i + 1];
    uint4 o;
    o.x = f2bf(a.x) | (f2bf(a.y) << 16);
    o.y = f2bf(a.z) | (f2bf(a.w) << 16);
    o.z = f2bf(b.x) | (f2bf(b.y) << 16);
    o.w = f2bf(b.z) | (f2bf(b.w) << 16);
    featb[i] = o;
}

// ---------------------------------------------------------------------------
// K1: per-block histogram over 196 bins
// ---------------------------------------------------------------------------
__global__ __launch_bounds__(256) void k1_hist(const int* __restrict__ dst,
                                               u32* __restrict__ ghist)
{
    __shared__ u32 h[NB];
    int tid = threadIdx.x;
    if (tid < NB) h[tid] = 0;
    __syncthreads();
    int base = blockIdx.x * EBLK;
    int n = min(EBLK, NE - base);
    for (int k = tid; k < n; k += 256)
        atomicAdd(&h[((u32)dst[base + k]) >> 8], 1u);
    __syncthreads();
    if (tid < NB) ghist[blockIdx.x * NB + tid] = h[tid];
}

// ---------------------------------------------------------------------------
// K2: per-bin exclusive scan over the 391 block counts -> bbase[blk][bin]
// ---------------------------------------------------------------------------
__global__ __launch_bounds__(256) void k2_scan(const u32* __restrict__ ghist,
                                               u32* __restrict__ bbase,
                                               u32* __restrict__ binTot)
{
    int gw = (blockIdx.x * 256 + threadIdx.x) >> 6;
    int lane = threadIdx.x & 63;
    if (gw >= NB) return;
    u32 run = 0;
    for (int c = 0; c < 7; ++c) {              // 7*64 = 448 >= 391
        int blk = c * 64 + lane;
        u32 v = (blk < NEB) ? ghist[blk * NB + gw] : 0;
        int incl = wave_incl_scan((int)v, lane);
        if (blk < NEB) bbase[blk * NB + gw] = (u32)incl - v + run;
        run += (u32)__shfl(incl, 63);
    }
    if (lane == 0) binTot[gw] = run;
}

// K2b: exclusive scan of 196 bin totals -> binStart[0..196]
__global__ void k2b_scan(const u32* __restrict__ binTot, u32* __restrict__ binStart)
{
    int lane = threadIdx.x;
    if (lane < 64) {
        u32 carry = 0;
        for (int c = 0; c < 4; ++c) {
            int idx = c * 64 + lane;
            u32 v = (idx < NB) ? binTot[idx] : 0;
            int incl = wave_incl_scan((int)v, lane);
            if (idx <= NB) binStart[idx] = (u32)incl - v + carry;
            carry += (u32)__shfl(incl, 63);
        }
    }
}

// ---------------------------------------------------------------------------
// K3: bin scatter with LDS reorder -> mostly-coalesced writes.
// ---------------------------------------------------------------------------
__global__ __launch_bounds__(256) void k3_scatter(const int* __restrict__ src,
                                                  const int* __restrict__ dst,
                                                  const float* __restrict__ ew,
                                                  const u32* __restrict__ bbase,
                                                  const u32* __restrict__ binStart,
                                                  u64* __restrict__ sorted)
{
    __shared__ u32 h[NB], eb[NB], ctr[NB], gb[NB];
    __shared__ u64 buf[EBLK];
    int tid = threadIdx.x;
    if (tid < NB) h[tid] = 0;
    __syncthreads();
    int base = blockIdx.x * EBLK;
    int n = min(EBLK, NE - base);
    for (int k = tid; k < n; k += 256)
        atomicAdd(&h[((u32)dst[base + k]) >> 8], 1u);
    __syncthreads();
    if (tid < 64) {
        u32 carry = 0;
        for (int c = 0; c < 4; ++c) {          // 4*64 = 256 >= 196
            int idx = c * 64 + tid;
            u32 v = (idx < NB) ? h[idx] : 0;
            int incl = wave_incl_scan((int)v, tid);
            if (idx < NB) { u32 e = (u32)incl - v + carry; eb[idx] = e; ctr[idx] = e; }
            carry += (u32)__shfl(incl, 63);
        }
    }
    if (tid < NB) gb[tid] = bbase[blockIdx.x * NB + tid] + binStart[tid];
    __syncthreads();
    for (int k = tid; k < n; k += 256) {
        int e = base + k;
        u32 d = (u32)dst[e], s = (u32)src[e];
        u64 rec = ((u64)((d << 16) | s) << 32) | (u64)__float_as_uint(ew[e]);
        u32 p = atomicAdd(&ctr[d >> 8], 1u);
        buf[p] = rec;
    }
    __syncthreads();
    for (int k = tid; k < n; k += 256) {
        u64 rec = buf[k];
        u32 bin = (u32)(rec >> 56);            // dst>>8
        sorted[gb[bin] + (u32)k - eb[bin]] = rec;
    }
}

// ---------------------------------------------------------------------------
// K3b: within-bin sort by node. One block per bin; LDS hist+scan+reorder;
// coalesced read & write. Emits node-sorted records + global nodeStart CSR.
// ---------------------------------------------------------------------------
__global__ __launch_bounds__(256) void k3b_nodesort(const u64* __restrict__ sorted,
                                                    const u32* __restrict__ binStart,
                                                    u64* __restrict__ sorted2,
                                                    u32* __restrict__ nodeStart)
{
    __shared__ u32 hcnt[256], hbase[257], ctr[256];
    __shared__ u64 buf[CAP3B];
    int tid = threadIdx.x;
    int bin = blockIdx.x;
    int beg = (int)binStart[bin];
    int n = (int)binStart[bin + 1] - beg;
    if (n > CAP3B) n = CAP3B;                  // 8-sigma guard, never expected

    hcnt[tid] = 0;
    __syncthreads();
    for (int k = tid; k < n; k += 256) {
        u64 rec = sorted[beg + k];
        int ln = (int)(rec >> 48) & 255;
        atomicAdd(&hcnt[ln], 1u);
    }
    __syncthreads();
    if (tid < 64) {
        u32 carry = 0;
        for (int c = 0; c < 4; ++c) {
            int idx = c * 64 + tid;
            u32 v = hcnt[idx];
            int incl = wave_incl_scan((int)v, tid);
            u32 ex = (u32)incl - v + carry;
            hbase[idx] = ex; ctr[idx] = ex;
            carry += (u32)__shfl(incl, 63);
        }
        if (tid == 63) hbase[256] = carry;
    }
    __syncthreads();
    for (int k = tid; k < n; k += 256) {
        u64 rec = sorted[beg + k];
        int ln = (int)(rec >> 48) & 255;
        u32 p = atomicAdd(&ctr[ln], 1u);
        buf[p] = rec;
    }
    __syncthreads();
    for (int k = tid; k < n; k += 256)
        sorted2[beg + k] = buf[k];
    nodeStart[(bin << 8) + tid] = (u32)beg + hbase[tid];
    if (bin == NB - 1 && tid == 0)
        nodeStart[NB << 8] = (u32)beg + hbase[256];
}

// ---------------------------------------------------------------------------
// K4: pure register gather. One 16-lane group per node (4 nodes/wave).
// No LDS, no atomics, no shuffles. 4-deep unroll -> 16 rows in flight/wave.
// ---------------------------------------------------------------------------
__global__ __launch_bounds__(256) void k4_gather(const uint2* __restrict__ fb,
                                                 const u64* __restrict__ sorted2,
                                                 const u32* __restrict__ nodeStart,
                                                 float* __restrict__ agg,
                                                 float* __restrict__ sW)
{
    int wv   = (blockIdx.x * 256 + threadIdx.x) >> 6;
    int lane = threadIdx.x & 63;
    int g    = lane >> 4;
    int li   = lane & 15;
    int node = wv * 4 + g;
    if (node >= NN) return;

    int e   = (int)nodeStart[node];
    int end = (int)nodeStart[node + 1];

    float4 acc = make_float4(0.f, 0.f, 0.f, 0.f);
    float ws = 0.f;

    for (; e + 3 < end; e += 4) {
        u64 r0 = sorted2[e],     r1 = sorted2[e + 1];
        u64 r2 = sorted2[e + 2], r3 = sorted2[e + 3];
        uint2 u0 = fb[(size_t)((u32)(r0 >> 32) & 0xffffu) * 16 + li];
        uint2 u1 = fb[(size_t)((u32)(r1 >> 32) & 0xffffu) * 16 + li];
        uint2 u2 = fb[(size_t)((u32)(r2 >> 32) & 0xffffu) * 16 + li];
        uint2 u3 = fb[(size_t)((u32)(r3 >> 32) & 0xffffu) * 16 + li];
        ws += __uint_as_float((u32)r0) + __uint_as_float((u32)r1)
            + __uint_as_float((u32)r2) + __uint_as_float((u32)r3);
        acc.x += __uint_as_float(u0.x << 16) + __uint_as_float(u1.x << 16)
               + __uint_as_float(u2.x << 16) + __uint_as_float(u3.x << 16);
        acc.y += __uint_as_float(u0.x & 0xffff0000u) + __uint_as_float(u1.x & 0xffff0000u)
               + __uint_as_float(u2.x & 0xffff0000u) + __uint_as_float(u3.x & 0xffff0000u);
        acc.z += __uint_as_float(u0.y << 16) + __uint_as_float(u1.y << 16)
               + __uint_as_float(u2.y << 16) + __uint_as_float(u3.y << 16);
        acc.w += __uint_as_float(u0.y & 0xffff0000u) + __uint_as_float(u1.y & 0xffff0000u)
               + __uint_as_float(u2.y & 0xffff0000u) + __uint_as_float(u3.y & 0xffff0000u);
    }
    for (; e < end; ++e) {
        u64 r0 = sorted2[e];
        uint2 u0 = fb[(size_t)((u32)(r0 >> 32) & 0xffffu) * 16 + li];
        ws += __uint_as_float((u32)r0);
        acc.x += __uint_as_float(u0.x << 16);
        acc.y += __uint_as_float(u0.x & 0xffff0000u);
        acc.z += __uint_as_float(u0.y << 16);
        acc.w += __uint_as_float(u0.y & 0xffff0000u);
    }

    *(float4*)&agg[(size_t)node * D + li * 4] = acc;
    if (li == 0) sW[node] = ws;
}

// ---------------------------------------------------------------------------
// Epilogue GEMM: out = feat@W1 + agg@W2 - sW ⊗ colsum(W2)
// ---------------------------------------------------------------------------
__global__ __launch_bounds__(256) void gemm_kernel(
    const float* __restrict__ feat,
    const float* __restrict__ agg,
    const float* __restrict__ sW,
    const float* __restrict__ W1,
    const float* __restrict__ W2,
    float* __restrict__ out)
{
    __shared__ float As[64][68];
    __shared__ float Bs[64][68];
    __shared__ float w1s[64 * 64];
    __shared__ float w2s[64 * 64];
    __shared__ float csum[64];
    __shared__ float swS[64];

    const int t = threadIdx.x;
    const int r0 = blockIdx.x * 64;
    const float4 z4 = make_float4(0.f, 0.f, 0.f, 0.f);

    for (int idx = t; idx < 1024; idx += 256) {
        int r = idx >> 4, c4 = idx & 15;
        int gr = r0 + r;
        float4 fv = z4, av = z4;
        if (gr < NN) {
            fv = *(const float4*)&feat[(size_t)gr * D + c4 * 4];
            av = *(const float4*)&agg [(size_t)gr * D + c4 * 4];
        }
        *(float4*)&As[r][c4 * 4] = fv;
        *(float4*)&Bs[r][c4 * 4] = av;
        ((float4*)w1s)[idx] = ((const float4*)W1)[idx];
        ((float4*)w2s)[idx] = ((const float4*)W2)[idx];
    }
    if (t < 64) swS[t] = (r0 + t < NN) ? sW[r0 + t] : 0.f;
    __syncthreads();
    if (t < 64) {
        float c = 0.f;
        for (int k = 0; k < 64; ++k) c += w2s[k * 64 + t];
        csum[t] = c;
    }
    __syncthreads();

    const int cg = t & 15;
    const int rg = t >> 4;
    const int j0 = cg * 4;
    const float4* w1v = (const float4*)w1s;
    const float4* w2v = (const float4*)w2s;

    float acc[4][4] = {};

    #pragma unroll 4
    for (int k4 = 0; k4 < 16; ++k4) {
        float4 av[4];
        #pragma unroll
        for (int i = 0; i < 4; ++i) av[i] = *(const float4*)&As[rg * 4 + i][k4 * 4];
        #pragma unroll
        for (int kk = 0; kk < 4; ++kk) {
            float4 wv = w1v[(k4 * 4 + kk) * 16 + cg];
            #pragma unroll
            for (int i = 0; i < 4; ++i) {
                float a = (&av[i].x)[kk];
                acc[i][0] += a * wv.x; acc[i][1] += a * wv.y;
                acc[i][2] += a * wv.z; acc[i][3] += a * wv.w;
            }
        }
    }
    #pragma unroll 4
    for (int k4 = 0; k4 < 16; ++k4) {
        float4 av[4];
        #pragma unroll
        for (int i = 0; i < 4; ++i) av[i] = *(const float4*)&Bs[rg * 4 + i][k4 * 4];
        #pragma unroll
        for (int kk = 0; kk < 4; ++kk) {
            float4 wv = w2v[(k4 * 4 + kk) * 16 + cg];
            #pragma unroll
            for (int i = 0; i < 4; ++i) {
                float a = (&av[i].x)[kk];
                acc[i][0] += a * wv.x; acc[i][1] += a * wv.y;
                acc[i][2] += a * wv.z; acc[i][3] += a * wv.w;
            }
        }
    }

    #pragma unroll
    for (int i = 0; i < 4; ++i) {
        int r = rg * 4 + i, gr = r0 + r;
        if (gr < NN) {
            float s = swS[r];
            float4 o;
            o.x = acc[i][0] - s * csum[j0 + 0];
            o.y = acc[i][1] - s * csum[j0 + 1];
            o.z = acc[i][2] - s * csum[j0 + 2];
            o.w = acc[i][3] - s * csum[j0 + 3];
            *(float4*)&out[(size_t)gr * D + j0] = o;
        }
    }
}

// ---------------------------------------------------------------------------
extern "C" void kernel_launch(void* const* d_in, const int* in_sizes, int n_in,
                              void* d_out, int out_size, void* d_ws, size_t ws_size,
                              hipStream_t stream)
{
    const float* feat = (const float*)d_in[0];
    const float* ew   = (const float*)d_in[1];
    const float* W1   = (const float*)d_in[2];
    const float* W2   = (const float*)d_in[3];
    const int*   src  = (const int*)  d_in[4];
    const int*   dst  = (const int*)  d_in[5];
    float* out = (float*)d_out;

    // workspace layout (~34 MB of 256 MB; all fully written before read)
    char* p = (char*)d_ws;
    size_t o = 0;
    auto take = [&](size_t bytes) { char* q = p + o; o = (o + bytes + 255) & ~(size_t)255; return q; };
    u64* sorted    = (u64*)take((size_t)NE * 8);             // 6.4 MB
    u64* sorted2   = (u64*)take((size_t)NE * 8);             // 6.4 MB
    u32* ghist     = (u32*)take((size_t)NEB * NB * 4);       // 306 KB
    u32* bbase     = (u32*)take((size_t)NEB * NB * 4);       // 306 KB
    u32* binTot    = (u32*)take((size_t)NB * 4);
    u32* binStart  = (u32*)take((size_t)(NB + 1) * 4);
    u32* nodeStart = (u32*)take((size_t)(NB * 256 + 1) * 4); // 200 KB
    float* agg     = (float*)take((size_t)NN * D * 4);       // 12.8 MB
    float* sW      = (float*)take((size_t)NN * 4);           // 200 KB
    uint4* featb   = (uint4*)take((size_t)NN * D * 2);       // 6.4 MB bf16 copy

    conv_kernel <<<(NN * D / 8 + 255) / 256, 256, 0, stream>>>(feat, featb);
    k1_hist     <<<NEB, 256, 0, stream>>>(dst, ghist);
    k2_scan     <<<(NB * 64 + 255) / 256, 256, 0, stream>>>(ghist, bbase, binTot);
    k2b_scan    <<<1, 256, 0, stream>>>(binTot, binStart);
    k3_scatter  <<<NEB, 256, 0, stream>>>(src, dst, ew, bbase, binStart, sorted);
    k3b_nodesort<<<NB, 256, 0, stream>>>(sorted, binStart, sorted2, nodeStart);
    k4_gather   <<<(NN + 15) / 16, 256, 0, stream>>>((const uint2*)featb, sorted2,
                                                     nodeStart, agg, sW);
    gemm_kernel <<<(NN + 63) / 64, 256, 0, stream>>>(feat, agg, sW, W1, W2, out);
}

// Round 8
// 69.209 us; speedup vs baseline: 1.2541x; 1.1780x over previous
//
#include <hip/hip_runtime.h>

#define NN 50000
#define NE 800000
#define D  64
#define NB 196            // bins of 256 nodes: bin = dst >> 8
#define EBLK 2048         // edges per hist/scatter block
#define NEB 391           // ceil(NE / EBLK)
#define CAP3B 4608        // per-bin record cap for k3b LDS
#define CONVB 1563        // ceil(NN*D/8 / 256) conv blocks in prep

typedef unsigned int u32;
typedef unsigned long long u64;
typedef __attribute__((ext_vector_type(8))) short bf16x8;
typedef __attribute__((ext_vector_type(4))) float f32x4;

__device__ __forceinline__ int wave_incl_scan(int v, int lane) {
    #pragma unroll
    for (int off = 1; off < 64; off <<= 1) {
        int t = __shfl_up(v, off);
        if (lane >= off) v += t;
    }
    return v;
}

__device__ __forceinline__ u32 f2bf(float x) {       // RNE bf16 -> low 16 bits
    u32 u = __float_as_uint(x);
    return (u + 0x7fffu + ((u >> 16) & 1u)) >> 16;
}

__device__ __forceinline__ bf16x8 as_bf8(uint4 u) {
    union { uint4 a; bf16x8 b; } x; x.a = u; return x.b;
}

// ---------------------------------------------------------------------------
// prep: blocks [0,CONVB) convert feat->featb (bf16); blocks [CONVB,+NEB) do
// the per-block bin histogram of dst.
// ---------------------------------------------------------------------------
__global__ __launch_bounds__(256) void prep_kernel(const float* __restrict__ feat,
                                                   uint4* __restrict__ featb,
                                                   const int* __restrict__ dst,
                                                   u32* __restrict__ ghist)
{
    __shared__ u32 h[NB];
    int tid = threadIdx.x;
    if (blockIdx.x < CONVB) {
        int i = blockIdx.x * 256 + tid;
        if (i >= NN * D / 8) return;
        const float4* f4 = (const float4*)feat;
        float4 a = f4[2 * i], b = f4[2 * i + 1];
        uint4 o;
        o.x = f2bf(a.x) | (f2bf(a.y) << 16);
        o.y = f2bf(a.z) | (f2bf(a.w) << 16);
        o.z = f2bf(b.x) | (f2bf(b.y) << 16);
        o.w = f2bf(b.z) | (f2bf(b.w) << 16);
        featb[i] = o;
    } else {
        int blk = blockIdx.x - CONVB;
        if (tid < NB) h[tid] = 0;
        __syncthreads();
        int base = blk * EBLK;
        int n = min(EBLK, NE - base);
        for (int k = tid; k < n; k += 256)
            atomicAdd(&h[((u32)dst[base + k]) >> 8], 1u);
        __syncthreads();
        if (tid < NB) ghist[blk * NB + tid] = h[tid];
    }
}

// ---------------------------------------------------------------------------
// K2: per-bin exclusive scan over the 391 block counts -> bbase[blk][bin]
// ---------------------------------------------------------------------------
__global__ __launch_bounds__(256) void k2_scan(const u32* __restrict__ ghist,
                                               u32* __restrict__ bbase,
                                               u32* __restrict__ binTot)
{
    int gw = (blockIdx.x * 256 + threadIdx.x) >> 6;
    int lane = threadIdx.x & 63;
    if (gw >= NB) return;
    u32 run = 0;
    for (int c = 0; c < 7; ++c) {              // 7*64 = 448 >= 391
        int blk = c * 64 + lane;
        u32 v = (blk < NEB) ? ghist[blk * NB + gw] : 0;
        int incl = wave_incl_scan((int)v, lane);
        if (blk < NEB) bbase[blk * NB + gw] = (u32)incl - v + run;
        run += (u32)__shfl(incl, 63);
    }
    if (lane == 0) binTot[gw] = run;
}

// K2b: exclusive scan of 196 bin totals -> binStart[0..196]
__global__ void k2b_scan(const u32* __restrict__ binTot, u32* __restrict__ binStart)
{
    int lane = threadIdx.x;
    if (lane < 64) {
        u32 carry = 0;
        for (int c = 0; c < 4; ++c) {
            int idx = c * 64 + lane;
            u32 v = (idx < NB) ? binTot[idx] : 0;
            int incl = wave_incl_scan((int)v, lane);
            if (idx <= NB) binStart[idx] = (u32)incl - v + carry;
            carry += (u32)__shfl(incl, 63);
        }
    }
}

// ---------------------------------------------------------------------------
// K3: bin scatter with LDS reorder -> mostly-coalesced writes.
// record: [dst:16][src:16][w_bits:32]
// ---------------------------------------------------------------------------
__global__ __launch_bounds__(256) void k3_scatter(const int* __restrict__ src,
                                                  const int* __restrict__ dst,
                                                  const float* __restrict__ ew,
                                                  const u32* __restrict__ bbase,
                                                  const u32* __restrict__ binStart,
                                                  u64* __restrict__ sorted)
{
    __shared__ u32 h[NB], eb[NB], ctr[NB], gb[NB];
    __shared__ u64 buf[EBLK];
    int tid = threadIdx.x;
    if (tid < NB) h[tid] = 0;
    __syncthreads();
    int base = blockIdx.x * EBLK;
    int n = min(EBLK, NE - base);
    for (int k = tid; k < n; k += 256)
        atomicAdd(&h[((u32)dst[base + k]) >> 8], 1u);
    __syncthreads();
    if (tid < 64) {
        u32 carry = 0;
        for (int c = 0; c < 4; ++c) {
            int idx = c * 64 + tid;
            u32 v = (idx < NB) ? h[idx] : 0;
            int incl = wave_incl_scan((int)v, tid);
            if (idx < NB) { u32 e = (u32)incl - v + carry; eb[idx] = e; ctr[idx] = e; }
            carry += (u32)__shfl(incl, 63);
        }
    }
    if (tid < NB) gb[tid] = bbase[blockIdx.x * NB + tid] + binStart[tid];
    __syncthreads();
    for (int k = tid; k < n; k += 256) {
        int e = base + k;
        u32 d = (u32)dst[e], s = (u32)src[e];
        u64 rec = ((u64)((d << 16) | s) << 32) | (u64)__float_as_uint(ew[e]);
        u32 p = atomicAdd(&ctr[d >> 8], 1u);
        buf[p] = rec;
    }
    __syncthreads();
    for (int k = tid; k < n; k += 256) {
        u64 rec = buf[k];
        u32 bin = (u32)(rec >> 56);
        sorted[gb[bin] + (u32)k - eb[bin]] = rec;
    }
}

// ---------------------------------------------------------------------------
// K3b: within-bin sort by node (LDS reorder). Emits node-sorted records +
// global nodeStart CSR.
// ---------------------------------------------------------------------------
__global__ __launch_bounds__(256) void k3b_nodesort(const u64* __restrict__ sorted,
                                                    const u32* __restrict__ binStart,
                                                    u64* __restrict__ sorted2,
                                                    u32* __restrict__ nodeStart)
{
    __shared__ u32 hcnt[256], hbase[257], ctr[256];
    __shared__ u64 buf[CAP3B];
    int tid = threadIdx.x;
    int bin = blockIdx.x;
    int beg = (int)binStart[bin];
    int n = (int)binStart[bin + 1] - beg;
    if (n > CAP3B) n = CAP3B;

    hcnt[tid] = 0;
    __syncthreads();
    for (int k = tid; k < n; k += 256) {
        u64 rec = sorted[beg + k];
        atomicAdd(&hcnt[(int)(rec >> 48) & 255], 1u);
    }
    __syncthreads();
    if (tid < 64) {
        u32 carry = 0;
        for (int c = 0; c < 4; ++c) {
            int idx = c * 64 + tid;
            u32 v = hcnt[idx];
            int incl = wave_incl_scan((int)v, tid);
            u32 ex = (u32)incl - v + carry;
            hbase[idx] = ex; ctr[idx] = ex;
            carry += (u32)__shfl(incl, 63);
        }
        if (tid == 63) hbase[256] = carry;
    }
    __syncthreads();
    for (int k = tid; k < n; k += 256) {
        u64 rec = sorted[beg + k];
        u32 p = atomicAdd(&ctr[(int)(rec >> 48) & 255], 1u);
        buf[p] = rec;
    }
    __syncthreads();
    for (int k = tid; k < n; k += 256)
        sorted2[beg + k] = buf[k];
    nodeStart[(bin << 8) + tid] = (u32)beg + hbase[tid];
    if (bin == NB - 1 && tid == 0)
        nodeStart[NB << 8] = (u32)beg + hbase[256];
}

// ---------------------------------------------------------------------------
// K4: pure register gather. One 16-lane group per node (4 nodes/wave).
// Emits agg in bf16 (same packed layout as featb) + sW fp32.
// ---------------------------------------------------------------------------
__global__ __launch_bounds__(256) void k4_gather(const uint2* __restrict__ fb,
                                                 const u64* __restrict__ sorted2,
                                                 const u32* __restrict__ nodeStart,
                                                 uint2* __restrict__ aggb,
                                                 float* __restrict__ sW)
{
    int wv   = (blockIdx.x * 256 + threadIdx.x) >> 6;
    int lane = threadIdx.x & 63;
    int g    = lane >> 4;
    int li   = lane & 15;
    int node = wv * 4 + g;
    if (node >= NN) return;

    int e   = (int)nodeStart[node];
    int end = (int)nodeStart[node + 1];

    float4 acc = make_float4(0.f, 0.f, 0.f, 0.f);
    float ws = 0.f;

    for (; e + 3 < end; e += 4) {
        u64 r0 = sorted2[e],     r1 = sorted2[e + 1];
        u64 r2 = sorted2[e + 2], r3 = sorted2[e + 3];
        uint2 u0 = fb[(size_t)((u32)(r0 >> 32) & 0xffffu) * 16 + li];
        uint2 u1 = fb[(size_t)((u32)(r1 >> 32) & 0xffffu) * 16 + li];
        uint2 u2 = fb[(size_t)((u32)(r2 >> 32) & 0xffffu) * 16 + li];
        uint2 u3 = fb[(size_t)((u32)(r3 >> 32) & 0xffffu) * 16 + li];
        ws += __uint_as_float((u32)r0) + __uint_as_float((u32)r1)
            + __uint_as_float((u32)r2) + __uint_as_float((u32)r3);
        acc.x += __uint_as_float(u0.x << 16) + __uint_as_float(u1.x << 16)
               + __uint_as_float(u2.x << 16) + __uint_as_float(u3.x << 16);
        acc.y += __uint_as_float(u0.x & 0xffff0000u) + __uint_as_float(u1.x & 0xffff0000u)
               + __uint_as_float(u2.x & 0xffff0000u) + __uint_as_float(u3.x & 0xffff0000u);
        acc.z += __uint_as_float(u0.y << 16) + __uint_as_float(u1.y << 16)
               + __uint_as_float(u2.y << 16) + __uint_as_float(u3.y << 16);
        acc.w += __uint_as_float(u0.y & 0xffff0000u) + __uint_as_float(u1.y & 0xffff0000u)
               + __uint_as_float(u2.y & 0xffff0000u) + __uint_as_float(u3.y & 0xffff0000u);
    }
    for (; e < end; ++e) {
        u64 r0 = sorted2[e];
        uint2 u0 = fb[(size_t)((u32)(r0 >> 32) & 0xffffu) * 16 + li];
        ws += __uint_as_float((u32)r0);
        acc.x += __uint_as_float(u0.x << 16);
        acc.y += __uint_as_float(u0.x & 0xffff0000u);
        acc.z += __uint_as_float(u0.y << 16);
        acc.w += __uint_as_float(u0.y & 0xffff0000u);
    }

    uint2 o;
    o.x = f2bf(acc.x) | (f2bf(acc.y) << 16);
    o.y = f2bf(acc.z) | (f2bf(acc.w) << 16);
    aggb[(size_t)node * 16 + li] = o;
    if (li == 0) sW[node] = ws;
}

// ---------------------------------------------------------------------------
// MFMA epilogue: out[50000][64] = [featb|aggb] @ [W1;W2]_bf16 - sW ⊗ csum(W2)
// One 16x16x32 wave-tile per 16 nodes; B-frags loop-invariant in VGPRs.
// A-frag layout: row = lane&15, k = 8*(lane>>4)+j (contiguous octet).
// D layout (m89-verified): col = lane&15, row = 4*(lane>>4)+reg.
// ---------------------------------------------------------------------------
__global__ __launch_bounds__(256) void gemm_mfma(
    const uint4* __restrict__ featb,   // [NN][8] uint4 = 64 bf16/row
    const uint4* __restrict__ aggb,    // [NN][8]
    const float* __restrict__ sW,
    const float* __restrict__ W1,
    const float* __restrict__ W2,
    float* __restrict__ out)
{
    __shared__ unsigned short wT[64][136];  // Wcat^T bf16, padded (272B rows)
    __shared__ float csp[4][64];
    __shared__ float csum[64];
    const int tid = threadIdx.x;

    // stage Wcat transposed as bf16
    for (int i = tid; i < 8192; i += 256) {
        int k = i >> 6, c = i & 63;
        float v = (k < 64) ? W1[i] : W2[i - 4096];
        wT[c][k] = (unsigned short)f2bf(v);
    }
    // csum partials (fp32, exact W2)
    {
        int c = tid & 63, kq = tid >> 6;
        float s = 0.f;
        for (int k = kq * 16; k < kq * 16 + 16; ++k) s += W2[k * 64 + c];
        csp[kq][c] = s;
    }
    __syncthreads();
    if (tid < 64) csum[tid] = csp[0][tid] + csp[1][tid] + csp[2][tid] + csp[3][tid];
    __syncthreads();

    int gw = blockIdx.x * 4 + (tid >> 6);    // global wave = node tile
    if (gw >= NN / 16) return;               // 3125 tiles exactly
    const int l  = tid & 63;
    const int lr = l & 15;
    const int q  = l >> 4;

    // loop-invariant B fragments: B[k][col], col = nt*16+lr, k = kk*32+q*8+j
    bf16x8 b[4][4];
    #pragma unroll
    for (int nt = 0; nt < 4; ++nt)
        #pragma unroll
        for (int kk = 0; kk < 4; ++kk)
            b[nt][kk] = *(const bf16x8*)&wT[nt * 16 + lr][kk * 32 + q * 8];

    const int m0 = gw * 16;
    const uint4* fr = featb + (size_t)(m0 + lr) * 8;
    const uint4* ar = aggb  + (size_t)(m0 + lr) * 8;

    // A fragments: kk=0,1 from featb (k<64), kk=2,3 from aggb (k>=64)
    bf16x8 a0 = as_bf8(fr[q]);
    bf16x8 a1 = as_bf8(fr[4 + q]);
    bf16x8 a2 = as_bf8(ar[q]);
    bf16x8 a3 = as_bf8(ar[4 + q]);

    f32x4 acc0 = {0.f, 0.f, 0.f, 0.f};
    f32x4 acc1 = acc0, acc2 = acc0, acc3 = acc0;

    acc0 = __builtin_amdgcn_mfma_f32_16x16x32_bf16(a0, b[0][0], acc0, 0, 0, 0);
    acc1 = __builtin_amdgcn_mfma_f32_16x16x32_bf16(a0, b[1][0], acc1, 0, 0, 0);
    acc2 = __builtin_amdgcn_mfma_f32_16x16x32_bf16(a0, b[2][0], acc2, 0, 0, 0);
    acc3 = __builtin_amdgcn_mfma_f32_16x16x32_bf16(a0, b[3][0], acc3, 0, 0, 0);

    acc0 = __builtin_amdgcn_mfma_f32_16x16x32_bf16(a1, b[0][1], acc0, 0, 0, 0);
    acc1 = __builtin_amdgcn_mfma_f32_16x16x32_bf16(a1, b[1][1], acc1, 0, 0, 0);
    acc2 = __builtin_amdgcn_mfma_f32_16x16x32_bf16(a1, b[2][1], acc2, 0, 0, 0);
    acc3 = __builtin_amdgcn_mfma_f32_16x16x32_bf16(a1, b[3][1], acc3, 0, 0, 0);

    acc0 = __builtin_amdgcn_mfma_f32_16x16x32_bf16(a2, b[0][2], acc0, 0, 0, 0);
    acc1 = __builtin_amdgcn_mfma_f32_16x16x32_bf16(a2, b[1][2], acc1, 0, 0, 0);
    acc2 = __builtin_amdgcn_mfma_f32_16x16x32_bf16(a2, b[2][2], acc2, 0, 0, 0);
    acc3 = __builtin_amdgcn_mfma_f32_16x16x32_bf16(a2, b[3][2], acc3, 0, 0, 0);

    acc0 = __builtin_amdgcn_mfma_f32_16x16x32_bf16(a3, b[0][3], acc0, 0, 0, 0);
    acc1 = __builtin_amdgcn_mfma_f32_16x16x32_bf16(a3, b[1][3], acc1, 0, 0, 0);
    acc2 = __builtin_amdgcn_mfma_f32_16x16x32_bf16(a3, b[2][3], acc2, 0, 0, 0);
    acc3 = __builtin_amdgcn_mfma_f32_16x16x32_bf16(a3, b[3][3], acc3, 0, 0, 0);

    // epilogue: out[m0 + q*4 + r][nt*16 + lr] = acc[nt][r] - sW*csum
    float4 sw4 = *(const float4*)&sW[m0 + q * 4];
    const float* swp = (const float*)&sw4;

    #pragma unroll
    for (int r = 0; r < 4; ++r) {
        size_t rowoff = (size_t)(m0 + q * 4 + r) * D;
        float s = swp[r];
        out[rowoff +  0 + lr] = acc0[r] - s * csum[ 0 + lr];
        out[rowoff + 16 + lr] = acc1[r] - s * csum[16 + lr];
        out[rowoff + 32 + lr] = acc2[r] - s * csum[32 + lr];
        out[rowoff + 48 + lr] = acc3[r] - s * csum[48 + lr];
    }
}

// ---------------------------------------------------------------------------
extern "C" void kernel_launch(void* const* d_in, const int* in_sizes, int n_in,
                              void* d_out, int out_size, void* d_ws, size_t ws_size,
                              hipStream_t stream)
{
    const float* feat = (const float*)d_in[0];
    const float* ew   = (const float*)d_in[1];
    const float* W1   = (const float*)d_in[2];
    const float* W2   = (const float*)d_in[3];
    const int*   src  = (const int*)  d_in[4];
    const int*   dst  = (const int*)  d_in[5];
    float* out = (float*)d_out;

    // workspace (~27 MB of 256 MB; every buffer fully written before read)
    char* p = (char*)d_ws;
    size_t o = 0;
    auto take = [&](size_t bytes) { char* q = p + o; o = (o + bytes + 255) & ~(size_t)255; return q; };
    u64* sorted    = (u64*)take((size_t)NE * 8);             // 6.4 MB
    u64* sorted2   = (u64*)take((size_t)NE * 8);             // 6.4 MB
    u32* ghist     = (u32*)take((size_t)NEB * NB * 4);
    u32* bbase     = (u32*)take((size_t)NEB * NB * 4);
    u32* binTot    = (u32*)take((size_t)NB * 4);
    u32* binStart  = (u32*)take((size_t)(NB + 1) * 4);
    u32* nodeStart = (u32*)take((size_t)(NB * 256 + 1) * 4);
    uint4* featb   = (uint4*)take((size_t)NN * D * 2);       // 6.4 MB bf16
    uint4* aggb    = (uint4*)take((size_t)NN * D * 2);       // 6.4 MB bf16
    float* sW      = (float*)take((size_t)NN * 4);

    prep_kernel <<<CONVB + NEB, 256, 0, stream>>>(feat, featb, dst, ghist);
    k2_scan     <<<(NB * 64 + 255) / 256, 256, 0, stream>>>(ghist, bbase, binTot);
    k2b_scan    <<<1, 256, 0, stream>>>(binTot, binStart);
    k3_scatter  <<<NEB, 256, 0, stream>>>(src, dst, ew, bbase, binStart, sorted);
    k3b_nodesort<<<NB, 256, 0, stream>>>(sorted, binStart, sorted2, nodeStart);
    k4_gather   <<<(NN + 15) / 16, 256, 0, stream>>>((const uint2*)featb, sorted2,
                                                     nodeStart, (uint2*)aggb, sW);
    gemm_mfma   <<<(NN / 16 + 3) / 4, 256, 0, stream>>>(featb, aggb, sW, W1, W2, out);
}